// Round 3
// baseline (343.566 us; speedup 1.0000x reference)
//
#include <hip/hip_runtime.h>

// Shapes (fixed by the problem)
#define LL 192
#define FF 2048

typedef __attribute__((__ext_vector_type__(8)))  __bf16 bf16x8;
typedef __attribute__((__ext_vector_type__(4)))  __bf16 bf16x4;
typedef __attribute__((__ext_vector_type__(4)))  float  f32x4;
typedef __attribute__((__ext_vector_type__(16))) float  f32x16;

#define MFMA16(a, b, c) __builtin_amdgcn_mfma_f32_16x16x32_bf16((a), (b), (c), 0, 0, 0)
#define MFMA32(a, b, c) __builtin_amdgcn_mfma_f32_32x32x16_bf16((a), (b), (c), 0, 0, 0)

// ---------------------------------------------------------------------------
// A0: prep — sig_frag in MFMA-C-layout register order, bf16 copies of
//     fc0_w / fc2_w, combined per-ff constants for the fused MLP epilogue.
// sig_frag layout: idx = ((w*6 + j)*64 + lane)*16 + r  holds sigmoid(se[s][t])
//   with s = 32w + (r&3) + 8*((r>>2)&3) + 4*(lane>>5),  t = 32j + (lane&31)
// (matches mfma_f32_32x32x16 C/D: col=lane&31, row=(r&3)+8*(r>>2)+4*(lane>>5))
// ---------------------------------------------------------------------------
__global__ void prep_kernel(const float* __restrict__ se,
                            const float* __restrict__ fc0w,
                            const float* __restrict__ fc2w,
                            const float* __restrict__ fc2b,
                            const float* __restrict__ bn2g,
                            const float* __restrict__ bn2b,
                            const float* __restrict__ fc3w,
                            __bf16* __restrict__ sig_frag,
                            __bf16* __restrict__ fc0w_bf,
                            __bf16* __restrict__ fc2w_bf,
                            float* __restrict__ h2,
                            float* __restrict__ bb2,
                            float* __restrict__ f3)
{
    int i0 = blockIdx.x * blockDim.x + threadIdx.x;
    int stride = gridDim.x * blockDim.x;
    const float c1 = rsqrtf(1.f + 1e-5f);
    for (int i = i0; i < LL * LL; i += stride) {
        int r = i & 15, lane = (i >> 4) & 63, jw = i >> 10;
        int j = jw % 6, w = jw / 6;
        int s = 32 * w + (r & 3) + 8 * ((r >> 2) & 3) + 4 * (lane >> 5);
        int t = 32 * j + (lane & 31);
        sig_frag[i] = (__bf16)(1.f / (1.f + __expf(-se[s * 192 + t])));
    }
    for (int i = i0; i < 128 * 128; i += stride)
        fc0w_bf[i] = (__bf16)fc0w[i];
    for (int i = i0; i < FF * LL; i += stride)
        fc2w_bf[i] = (__bf16)fc2w[i];
    for (int i = i0; i < FF; i += stride) {
        float h = bn2g[i] * c1;
        h2[i]  = h;
        bb2[i] = fc2b[i] * h + bn2b[i];
        f3[i]  = fc3w[i];
    }
}

// ---------------------------------------------------------------------------
// A1: projection y = X @ fc0_w^T + fc0_b.
//   bx < 384 : query rows -> qfrag in B-operand fragment order
//              qfrag[q][((j*8+kstep)*64 + (t&31)+32*((d>>3)&1))*8 + (d&7)]
//   bx >= 384: key rows   -> kfeat row-major [24576][128]
// ---------------------------------------------------------------------------
__launch_bounds__(256, 2)
__global__ void qkproj_kernel(const float* __restrict__ qf,
                              const float* __restrict__ gf,
                              const __bf16* __restrict__ w_bf,
                              const float* __restrict__ bias,
                              __bf16* __restrict__ kfeat,
                              __bf16* __restrict__ qfrag)
{
    __shared__ __bf16 Xs[32][136];
    __shared__ __bf16 Ws[128][136];
    int bx = blockIdx.x, tid = threadIdx.x;
    const float* src = (bx < 384) ? (qf + (size_t)bx * (32 * 128))
                                  : (gf + (size_t)(bx - 384) * (32 * 128));
#pragma unroll
    for (int it = 0; it < 4; ++it) {
        int e = (it * 256 + tid) * 4;
        int r = e >> 7, c = e & 127;
        float4 v = *reinterpret_cast<const float4*>(src + e);
        bf16x4 xv;
        xv[0] = (__bf16)v.x; xv[1] = (__bf16)v.y;
        xv[2] = (__bf16)v.z; xv[3] = (__bf16)v.w;
        *reinterpret_cast<bf16x4*>(&Xs[r][c]) = xv;
    }
#pragma unroll
    for (int it = 0; it < 8; ++it) {
        int e = (it * 256 + tid) * 8;
        int r = e >> 7, c = e & 127;
        *reinterpret_cast<bf16x8*>(&Ws[r][c]) =
            *reinterpret_cast<const bf16x8*>(w_bf + e);
    }
    __syncthreads();

    int wv = tid >> 6, lane = tid & 63, quad = lane >> 4, l16 = lane & 15;
    int n0 = wv * 32;
    f32x4 acc[2][2];
#pragma unroll
    for (int m = 0; m < 2; ++m)
#pragma unroll
        for (int n = 0; n < 2; ++n) acc[m][n] = (f32x4){0.f, 0.f, 0.f, 0.f};
#pragma unroll
    for (int ks = 0; ks < 4; ++ks) {
        bf16x8 a0 = *reinterpret_cast<const bf16x8*>(&Xs[l16][ks * 32 + quad * 8]);
        bf16x8 a1 = *reinterpret_cast<const bf16x8*>(&Xs[16 + l16][ks * 32 + quad * 8]);
        bf16x8 b0 = *reinterpret_cast<const bf16x8*>(&Ws[n0 + l16][ks * 32 + quad * 8]);
        bf16x8 b1 = *reinterpret_cast<const bf16x8*>(&Ws[n0 + 16 + l16][ks * 32 + quad * 8]);
        acc[0][0] = MFMA16(a0, b0, acc[0][0]);
        acc[0][1] = MFMA16(a0, b1, acc[0][1]);
        acc[1][0] = MFMA16(a1, b0, acc[1][0]);
        acc[1][1] = MFMA16(a1, b1, acc[1][1]);
    }
#pragma unroll
    for (int mt = 0; mt < 2; ++mt)
#pragma unroll
        for (int nt = 0; nt < 2; ++nt) {
            int d = n0 + nt * 16 + l16;
            float bv = bias[d];
#pragma unroll
            for (int r = 0; r < 4; ++r) {
                int row = bx * 32 + mt * 16 + quad * 4 + r;
                __bf16 val = (__bf16)(acc[mt][nt][r] + bv);
                if (bx < 384) {
                    int qi = row / 192, tl = row % 192;
                    int addr = qi * 24576 +
                        (((tl >> 5) * 8 + (d >> 4)) * 64 +
                         (tl & 31) + 32 * ((d >> 3) & 1)) * 8 + (d & 7);
                    qfrag[addr] = val;
                } else {
                    int rk = row - 12288;
                    kfeat[(size_t)rk * 128 + d] = val;
                }
            }
        }
}

// ---------------------------------------------------------------------------
// B: per-pair score GEMM + sigmoid-modulation + dual max-reduce (dominant).
//    384 threads = 6 waves; wave w owns rows s in [32w, 32w+32) x all 192 t.
//    32x32x16 MFMA, A (key rows) straight from L2, B (query) from LDS in
//    fragment order (conflict-free sequential reads), sig from sig_frag in
//    C-register order.  LDS 81.4 KB -> 2 blocks/CU.
// ---------------------------------------------------------------------------
__launch_bounds__(384, 3)
__global__ void score_kernel(const __bf16* __restrict__ kfeat,
                             const __bf16* __restrict__ qfrag,
                             const __bf16* __restrict__ sig_frag,
                             const float* __restrict__ bn1g,
                             const float* __restrict__ bn1b,
                             __bf16* __restrict__ Sred)
{
    __shared__ __bf16 qf[24576];        // Q fragments: 49,152 B
    __shared__ float  rowmax[192][33];  // 25,344 B  (per-s, 32 col-classes)
    __shared__ float  colmax[192][9];   // 6,912 B   (per-t, 6 wave s-slices)

    int tid = threadIdx.x;
    int q = blockIdx.x >> 4;
    int kbase = (blockIdx.x & 15) << 3;
    int w = tid >> 6, lane = tid & 63, half = lane >> 5, col = lane & 31;

    const __bf16* qsrc = qfrag + (size_t)q * 24576;
#pragma unroll
    for (int it = 0; it < 8; ++it) {
        int e = (it * 384 + tid) * 8;
        *reinterpret_cast<bf16x8*>(&qf[e]) =
            *reinterpret_cast<const bf16x8*>(qsrc + e);
    }
    const float g1c = bn1g[0] * rsqrtf(1.f + 1e-5f);
    const float b1v = bn1b[0];
    const __bf16* kbaseptr = kfeat + ((size_t)(32 * w + col)) * 128 + half * 8;
    const __bf16* sgptr = sig_frag + ((w * 6) * 64 + lane) * 16;
    __syncthreads();

    for (int kk = 0; kk < 8; ++kk) {
        int kidx = kbase + kk;
        const __bf16* kp = kbaseptr + (size_t)kidx * (192 * 128);

        // sig for this wave's quadrant (register order; L2-hot, reload per pair
        // so the VGPR cap from __launch_bounds__ holds)
        bf16x8 sg[6][2];
#pragma unroll
        for (int j = 0; j < 6; ++j) {
            sg[j][0] = *reinterpret_cast<const bf16x8*>(sgptr + j * 1024);
            sg[j][1] = *reinterpret_cast<const bf16x8*>(sgptr + j * 1024 + 8);
        }

        f32x16 acc[6];
#pragma unroll
        for (int j = 0; j < 6; ++j)
#pragma unroll
            for (int r = 0; r < 16; ++r) acc[j][r] = 0.f;

#pragma unroll
        for (int ks = 0; ks < 8; ++ks) {
            bf16x8 a = *reinterpret_cast<const bf16x8*>(kp + ks * 16);
#pragma unroll
            for (int j = 0; j < 6; ++j) {
                bf16x8 b = *reinterpret_cast<const bf16x8*>(
                    &qf[(j * 8 + ks) * 512 + lane * 8]);
                acc[j] = MFMA32(a, b, acc[j]);
            }
        }

        // Epilogue: v = acc * sig;  intra-lane max trees.
        float rm[16];
#pragma unroll
        for (int r = 0; r < 16; ++r) rm[r] = -3.0e38f;
        float cm[6];
#pragma unroll
        for (int j = 0; j < 6; ++j) {
            float cmj = -3.0e38f;
#pragma unroll
            for (int r = 0; r < 16; ++r) {
                float v = acc[j][r] * (float)(sg[j][r >> 3][r & 7]);
                rm[r] = fmaxf(rm[r], v);
                cmj = fmaxf(cmj, v);
            }
            cm[j] = cmj;
        }
#pragma unroll
        for (int j = 0; j < 6; ++j)
            cm[j] = fmaxf(cm[j], __shfl_xor(cm[j], 32, 64));
        if (half == 0) {
#pragma unroll
            for (int j = 0; j < 6; ++j)
                colmax[32 * j + col][w] = cm[j];
        }
#pragma unroll
        for (int r = 0; r < 16; ++r) {
            int s = 32 * w + (r & 3) + 8 * ((r >> 2) & 3) + 4 * half;
            rowmax[s][col] = rm[r];
        }
        __syncthreads();   // partials ready

        size_t pb = (size_t)(q * 128 + kidx) * 384;
        if (tid < 192) {                 // waves 0-2: max over s, indexed by t
            float m0 = colmax[tid][0];
#pragma unroll
            for (int u = 1; u < 6; ++u) m0 = fmaxf(m0, colmax[tid][u]);
            Sred[pb + tid] = (__bf16)(m0 * g1c + b1v);
        } else {                         // waves 3-5: max over t, indexed by s
            int s = tid - 192;
            float m1 = rowmax[s][0];
#pragma unroll
            for (int u = 1; u < 32; ++u) m1 = fmaxf(m1, rowmax[s][u]);
            Sred[pb + 192 + s] = (__bf16)(m1 * g1c + b1v);
        }
        __syncthreads();   // combine reads done; arrays free for next pair
    }
}

// ---------------------------------------------------------------------------
// C: fused fc2 + bn2 + relu + fc3 + pair-sum + bn3.  64 Sred rows per block,
//    8 waves x 256 ff-cols each, fc3 dot accumulated inline.
// ---------------------------------------------------------------------------
__launch_bounds__(512, 2)
__global__ void mlp_kernel(const __bf16* __restrict__ Sred,
                           const __bf16* __restrict__ fc2w_bf,
                           const float* __restrict__ h2,
                           const float* __restrict__ bb2,
                           const float* __restrict__ f3,
                           const float* __restrict__ fc3b,
                           const float* __restrict__ bn3g,
                           const float* __restrict__ bn3b,
                           float* __restrict__ out)
{
    __shared__ __bf16 As[64][200];       // 64 rows x 192 (+8 pad)
    __shared__ float  psum_lds[8][64];
    int bx = blockIdx.x, tid = threadIdx.x;
    const __bf16* asrc = Sred + (size_t)bx * (64 * 192);
#pragma unroll
    for (int it = 0; it < 3; ++it) {     // 12288 bf16
        int e = (it * 512 + tid) * 8;
        int r = e / 192, c = e - r * 192;
        *reinterpret_cast<bf16x8*>(&As[r][c]) =
            *reinterpret_cast<const bf16x8*>(asrc + e);
    }
    __syncthreads();

    int wv = tid >> 6, lane = tid & 63, quad = lane >> 4, l16 = lane & 15;
    bf16x8 af[4][6];                     // hoisted A-fragments (reused 16x)
#pragma unroll
    for (int m = 0; m < 4; ++m)
#pragma unroll
        for (int kk = 0; kk < 6; ++kk)
            af[m][kk] = *reinterpret_cast<const bf16x8*>(
                &As[m * 16 + l16][kk * 32 + quad * 8]);

    float ps[4][4] = {{0.f,0.f,0.f,0.f},{0.f,0.f,0.f,0.f},
                      {0.f,0.f,0.f,0.f},{0.f,0.f,0.f,0.f}};
    for (int nt = 0; nt < 16; ++nt) {
        int n0 = wv * 256 + nt * 16;
        f32x4 acc[4];
#pragma unroll
        for (int m = 0; m < 4; ++m) acc[m] = (f32x4){0.f, 0.f, 0.f, 0.f};
        const __bf16* bp = fc2w_bf + (size_t)(n0 + l16) * 192 + quad * 8;
#pragma unroll
        for (int kk = 0; kk < 6; ++kk) {
            bf16x8 b = *reinterpret_cast<const bf16x8*>(bp + kk * 32);
#pragma unroll
            for (int m = 0; m < 4; ++m) acc[m] = MFMA16(af[m][kk], b, acc[m]);
        }
        int n = n0 + l16;
        float hh = h2[n], bb = bb2[n], ffv = f3[n];
#pragma unroll
        for (int m = 0; m < 4; ++m)
#pragma unroll
            for (int r = 0; r < 4; ++r)
                ps[m][r] += fmaxf(acc[m][r] * hh + bb, 0.f) * ffv;
    }
#pragma unroll
    for (int m = 0; m < 4; ++m)
#pragma unroll
        for (int r = 0; r < 4; ++r) {
            float v = ps[m][r];
            v += __shfl_xor(v, 1, 64);
            v += __shfl_xor(v, 2, 64);
            v += __shfl_xor(v, 4, 64);
            v += __shfl_xor(v, 8, 64);
            if (l16 == 0) psum_lds[wv][m * 16 + quad * 4 + r] = v;
        }
    __syncthreads();
    if (tid < 32) {
        float s = 0.f;
#pragma unroll
        for (int w = 0; w < 8; ++w)
            s += psum_lds[w][2 * tid] + psum_lds[w][2 * tid + 1];
        const float c1 = rsqrtf(1.f + 1e-5f);
        out[bx * 32 + tid] = (s + 2.f * fc3b[0]) * (bn3g[0] * c1) + bn3b[0];
    }
}

// ---------------------------------------------------------------------------
extern "C" void kernel_launch(void* const* d_in, const int* in_sizes, int n_in,
                              void* d_out, int out_size, void* d_ws, size_t ws_size,
                              hipStream_t stream)
{
    const float* q_feat = (const float*)d_in[0];
    const float* g_feat = (const float*)d_in[1];
    const float* se     = (const float*)d_in[2];
    const float* fc0w   = (const float*)d_in[3];
    const float* fc0b   = (const float*)d_in[4];
    const float* fc2w   = (const float*)d_in[5];
    const float* fc2b   = (const float*)d_in[6];
    const float* fc3w   = (const float*)d_in[7];
    const float* fc3b   = (const float*)d_in[8];
    const float* bn1g   = (const float*)d_in[9];
    const float* bn1b   = (const float*)d_in[10];
    const float* bn2g   = (const float*)d_in[11];
    const float* bn2b   = (const float*)d_in[12];
    const float* bn3g   = (const float*)d_in[13];
    const float* bn3b   = (const float*)d_in[14];
    float* out = (float*)d_out;

    char* ws = (char*)d_ws;
    __bf16* kfeat    = (__bf16*)(ws);                 //  6,291,456 B
    __bf16* qfrag    = (__bf16*)(ws +  6291456);      //  3,145,728 B
    __bf16* sig_frag = (__bf16*)(ws +  9437184);      //     73,728 B
    __bf16* fc0w_bf  = (__bf16*)(ws +  9510912);      //     32,768 B
    __bf16* fc2w_bf  = (__bf16*)(ws +  9543680);      //    786,432 B
    float*  h2       = (float*) (ws + 10330112);      //      8,192 B
    float*  bb2      = (float*) (ws + 10338304);      //      8,192 B
    float*  f3       = (float*) (ws + 10346496);      //      8,192 B
    __bf16* Sred     = (__bf16*)(ws + 10354688);      //  6,291,456 B (16.65 MB total)

    prep_kernel<<<256, 256, 0, stream>>>(se, fc0w, fc2w, fc2b, bn2g, bn2b, fc3w,
                                         sig_frag, fc0w_bf, fc2w_bf, h2, bb2, f3);
    qkproj_kernel<<<1152, 256, 0, stream>>>(q_feat, g_feat, fc0w_bf, fc0b,
                                            kfeat, qfrag);
    score_kernel<<<1024, 384, 0, stream>>>(kfeat, qfrag, sig_frag, bn1g, bn1b, Sred);
    mlp_kernel<<<256, 512, 0, stream>>>(Sred, fc2w_bf, h2, bb2, f3,
                                        fc3b, bn3g, bn3b, out);
}